// Round 6
// baseline (4263.301 us; speedup 1.0000x reference)
//
#include <hip/hip_runtime.h>
#include <math.h>

typedef _Float16 f16;
typedef f16 half8 __attribute__((ext_vector_type(8)));
typedef float f32x4 __attribute__((ext_vector_type(4)));

// Problem sizes: B=4, T=2048, G=8, D=128, V=1024
#define BT 8192
#define NG 8
#define ND 128
#define NV 1024
#define MARGIN 0.02f

// d_out layout (float32): ids[65536] | quantized_st[8388608] | 3 losses
#define OUT_IDS 0
#define OUT_Q   65536
#define OUT_L   (65536 + 8388608)

// ws float offsets (~0.6 MB)
#define OFF_C2A   0          // c2 [v*8+g] (recheck layout)      (8192)
#define OFF_C2B   8192       // c2 [g*NV+v] (gemm layout)        (8192)
#define OFF_IDS   16384      // ids int                          (65536)
#define OFF_LOSS  81920      // per-token loss                   (8192)
#define OFF_CNT   90112      // flag count                       (8)
#define OFF_FLAGS 90120      // flag list                        (65536)

// ---------------------------------------------------------------------------
// c2: both layouts. Arithmetic identical to R1 (pairwise-8 accs, mul+add).
// ---------------------------------------------------------------------------
__global__ __launch_bounds__(256) void c2_kernel(const float* __restrict__ cb,
                                                 float* __restrict__ c2a,
                                                 float* __restrict__ c2b) {
    int idx = blockIdx.x * 256 + threadIdx.x;   // idx = v*8+g
    int v = idx >> 3, g = idx & 7;
    const float* row = cb + (size_t)idx * ND;
    float r[8];
#pragma unroll
    for (int j = 0; j < 8; ++j) r[j] = 0.0f;
#pragma unroll
    for (int k = 0; k < 16; ++k)
#pragma unroll
        for (int j = 0; j < 8; ++j) {
            float c = row[k * 8 + j];
            r[j] = __fadd_rn(r[j], __fmul_rn(c, c));
        }
    float s = __fadd_rn(
        __fadd_rn(__fadd_rn(r[0], r[1]), __fadd_rn(r[2], r[3])),
        __fadd_rn(__fadd_rn(r[4], r[5]), __fadd_rn(r[6], r[7])));
    c2a[idx] = s;
    c2b[g * NV + v] = s;
}

// ---------------------------------------------------------------------------
// MFMA distance GEMM, A-resident: block = 128 tokens x one g, loops 8 code
// tiles. A read once (fp32->fp16 split in regs); B staged per tile from
// L2-resident fp32 cb (split during staging, XOR-swizzled LDS).
// b = tt*8+g  ->  XCD b%8 serves one g (cb[g] fp32 = 512 KB, L2-fits).
// s = xh*ch + xl*ch + xh*cl (3 chained mfma_f32_16x16x32_f16); d' = c2-2s.
// Running per-token (d1,id,cnt) across tiles; writes ids + near-tie flags
// directly. Ties/near-ties => cnt>=2 => exact recheck (sound).
// ---------------------------------------------------------------------------
__global__ __launch_bounds__(256, 2) void mfma_gemm(
    const float* __restrict__ x, const float* __restrict__ cb,
    const float* __restrict__ c2b, const int* __restrict__ pad,
    int* __restrict__ ws_ids, float* __restrict__ out_ids,
    int* __restrict__ cnt, int* __restrict__ flags) {
    __shared__ f16 Bh[128 * 128];
    __shared__ f16 Bl[128 * 128];

    const int tid = threadIdx.x;
    const int b = blockIdx.x;
    const int g = b & 7;
    const int tt = b >> 3;
    const int tok0 = tt * 128;
    const int lane = tid & 63;
    const int w = tid >> 6;
    const int l15 = lane & 15, l4 = lane >> 4;

    // ---- A: load fp32 once, split to fp16 h/l in registers ----
    half8 ah[4][2], al[4][2];   // [kk][ti]
#pragma unroll
    for (int kk = 0; kk < 4; ++kk)
#pragma unroll
        for (int ti = 0; ti < 2; ++ti) {
            const float* ap = x + ((size_t)(tok0 + w * 32 + ti * 16 + l15) * NG + g) * ND
                              + kk * 32 + l4 * 8;
            float4 p0 = *(const float4*)ap, p1 = *(const float4*)(ap + 4);
            float v[8] = {p0.x, p0.y, p0.z, p0.w, p1.x, p1.y, p1.z, p1.w};
            half8 h, l;
#pragma unroll
            for (int j = 0; j < 8; ++j) {
                f16 hh = (f16)v[j];
                h[j] = hh;
                l[j] = (f16)(v[j] - (float)hh);
            }
            ah[kk][ti] = h;
            al[kk][ti] = l;
        }

    float d1r[2][4];
    int idr[2][4], cntr[2][4];
#pragma unroll
    for (int ti = 0; ti < 2; ++ti)
#pragma unroll
        for (int r = 0; r < 4; ++r) {
            d1r[ti][r] = INFINITY;
            idr[ti][r] = 0;
            cntr[ti][r] = 0;
        }

#pragma unroll 1
    for (int cn = 0; cn < 8; ++cn) {
        const int vb0 = cn * 128;
        __syncthreads();
        // stage B tile: fp32 from L2, split + swizzle ((k16 ^ row&7) half8 slots)
#pragma unroll
        for (int i = 0; i < 8; ++i) {
            int s = i * 256 + tid;
            int row = s >> 4, k16 = s & 15;
            const float* cp = cb + ((size_t)(vb0 + row) * NG + g) * ND + k16 * 8;
            float4 q0 = *(const float4*)cp, q1 = *(const float4*)(cp + 4);
            float v[8] = {q0.x, q0.y, q0.z, q0.w, q1.x, q1.y, q1.z, q1.w};
            half8 h, l;
#pragma unroll
            for (int j = 0; j < 8; ++j) {
                f16 hh = (f16)v[j];
                h[j] = hh;
                l[j] = (f16)(v[j] - (float)hh);
            }
            int lo = row * 128 + ((k16 ^ (row & 7)) << 3);
            *(half8*)&Bh[lo] = h;
            *(half8*)&Bl[lo] = l;
        }
        float c2r[8];
#pragma unroll
        for (int tj = 0; tj < 8; ++tj)
            c2r[tj] = c2b[(size_t)g * NV + vb0 + tj * 16 + l15];
        __syncthreads();

        f32x4 acc[2][8];
#pragma unroll
        for (int ti = 0; ti < 2; ++ti)
#pragma unroll
            for (int tj = 0; tj < 8; ++tj) acc[ti][tj] = (f32x4){0.f, 0.f, 0.f, 0.f};

#pragma unroll
        for (int kk = 0; kk < 4; ++kk) {
            {
                half8 bh[8];
#pragma unroll
                for (int tj = 0; tj < 8; ++tj) {
                    int rw = tj * 16 + l15;
                    bh[tj] = *(half8*)&Bh[rw * 128 + (((kk * 4 + l4) ^ (rw & 7)) << 3)];
                }
#pragma unroll
                for (int ti = 0; ti < 2; ++ti)
#pragma unroll
                    for (int tj = 0; tj < 8; ++tj)
                        acc[ti][tj] = __builtin_amdgcn_mfma_f32_16x16x32_f16(
                            ah[kk][ti], bh[tj], acc[ti][tj], 0, 0, 0);
#pragma unroll
                for (int ti = 0; ti < 2; ++ti)
#pragma unroll
                    for (int tj = 0; tj < 8; ++tj)
                        acc[ti][tj] = __builtin_amdgcn_mfma_f32_16x16x32_f16(
                            al[kk][ti], bh[tj], acc[ti][tj], 0, 0, 0);
            }
            {
                half8 bl[8];
#pragma unroll
                for (int tj = 0; tj < 8; ++tj) {
                    int rw = tj * 16 + l15;
                    bl[tj] = *(half8*)&Bl[rw * 128 + (((kk * 4 + l4) ^ (rw & 7)) << 3)];
                }
#pragma unroll
                for (int ti = 0; ti < 2; ++ti)
#pragma unroll
                    for (int tj = 0; tj < 8; ++tj)
                        acc[ti][tj] = __builtin_amdgcn_mfma_f32_16x16x32_f16(
                            ah[kk][ti], bl[tj], acc[ti][tj], 0, 0, 0);
            }
        }

        // epilogue: d' = c2 - 2s; in-wave argmin + margin count; merge running
#pragma unroll
        for (int ti = 0; ti < 2; ++ti) {
#pragma unroll
            for (int r = 0; r < 4; ++r) {
                float d[8];
#pragma unroll
                for (int tj = 0; tj < 8; ++tj)
                    d[tj] = fmaf(-2.0f, acc[ti][tj][r], c2r[tj]);
                float d1 = d[0];
                int id = vb0 + l15;
#pragma unroll
                for (int tj = 1; tj < 8; ++tj)
                    if (d[tj] < d1) { d1 = d[tj]; id = vb0 + tj * 16 + l15; }
#pragma unroll
                for (int m = 1; m < 16; m <<= 1) {
                    float od = __shfl_xor(d1, m);
                    int oid = __shfl_xor(id, m);
                    if (od < d1) { d1 = od; id = oid; }
                }
                float thr = d1 + MARGIN;
                int cl = 0;
#pragma unroll
                for (int tj = 0; tj < 8; ++tj) cl += (d[tj] < thr) ? 1 : 0;
#pragma unroll
                for (int m = 1; m < 16; m <<= 1) cl += __shfl_xor(cl, m);
                if (d1 < d1r[ti][r]) { d1r[ti][r] = d1; idr[ti][r] = id; }
                cntr[ti][r] += cl;
            }
        }
    }

    // write ids + flags (lane group leader per token)
    if (l15 == 0) {
#pragma unroll
        for (int ti = 0; ti < 2; ++ti)
#pragma unroll
            for (int r = 0; r < 4; ++r) {
                int tok = tok0 + w * 32 + ti * 16 + l4 * 4 + r;
                int idx = tok * NG + g;
                int id = idr[ti][r];
                ws_ids[idx] = id;
                out_ids[idx] = pad[tok] ? -1.0f : (float)id;
                if (cntr[ti][r] >= 2) {
                    int pos = atomicAdd(cnt, 1);
                    flags[pos] = idx;
                }
            }
    }
}

// ---------------------------------------------------------------------------
// exact fp32 recheck for flagged (token,g): R1-identical arithmetic,
// including in-place x2 with the exact pairwise-8 order.
// ---------------------------------------------------------------------------
__global__ __launch_bounds__(256, 1) void recheck(
    const float* __restrict__ x, const int* __restrict__ pad,
    const float* __restrict__ cb, const float* __restrict__ c2w,
    const int* __restrict__ cnt, const int* __restrict__ flags,
    int* __restrict__ ws_ids, float* __restrict__ out_ids) {
    const int lane = threadIdx.x & 63;
    const int wid = (blockIdx.x * 256 + threadIdx.x) >> 6;
    const int nw = gridDim.x * 4;
    const int n_f = cnt[0];
    for (int f = wid; f < n_f; f += nw) {
        int idx = flags[f];
        int g = idx & 7;
        const float4* xr = (const float4*)(x + (size_t)idx * ND);
        float4 xv[32];
#pragma unroll
        for (int i = 0; i < 32; ++i) xv[i] = xr[i];
        // exact x2 (R1 order)
        float rr[8];
#pragma unroll
        for (int j = 0; j < 8; ++j) rr[j] = 0.0f;
#pragma unroll
        for (int i = 0; i < 32; ++i) {
            int j0 = (i * 4) & 7;
            rr[j0 + 0] = __fadd_rn(rr[j0 + 0], __fmul_rn(xv[i].x, xv[i].x));
            rr[j0 + 1] = __fadd_rn(rr[j0 + 1], __fmul_rn(xv[i].y, xv[i].y));
            rr[j0 + 2] = __fadd_rn(rr[j0 + 2], __fmul_rn(xv[i].z, xv[i].z));
            rr[j0 + 3] = __fadd_rn(rr[j0 + 3], __fmul_rn(xv[i].w, xv[i].w));
        }
        float x2v = __fadd_rn(
            __fadd_rn(__fadd_rn(rr[0], rr[1]), __fadd_rn(rr[2], rr[3])),
            __fadd_rn(__fadd_rn(rr[4], rr[5]), __fadd_rn(rr[6], rr[7])));
        float best = INFINITY;
        int bid = 0;
        for (int j = 0; j < 16; ++j) {
            int c = lane + 64 * j;
            const float4* cr = (const float4*)(cb + ((size_t)c * NG + g) * ND);
            float s = 0.f;
#pragma unroll
            for (int i = 0; i < 32; ++i) {
                float4 q = cr[i];
                s = fmaf(xv[i].x, q.x, s);
                s = fmaf(xv[i].y, q.y, s);
                s = fmaf(xv[i].z, q.z, s);
                s = fmaf(xv[i].w, q.w, s);
            }
            float d = __fadd_rn(__fsub_rn(x2v, __fmul_rn(2.0f, s)),
                                c2w[(size_t)c * NG + g]);
            if (d < best) { best = d; bid = c; }
        }
#pragma unroll
        for (int m = 1; m < 64; m <<= 1) {
            float od = __shfl_xor(best, m);
            int ob = __shfl_xor(bid, m);
            if (od < best || (od == best && ob < bid)) { best = od; bid = ob; }
        }
        if (lane == 0) {
            ws_ids[idx] = bid;
            out_ids[idx] = pad[idx >> 3] ? -1.0f : (float)bid;
        }
    }
}

// ---------------------------------------------------------------------------
// gather quantized (masked), write quantized_st, per-token loss partial
// ---------------------------------------------------------------------------
__global__ __launch_bounds__(256) void gather_kernel(
    const float* __restrict__ x, const int* __restrict__ pad,
    const float* __restrict__ cb, const int* __restrict__ ws_ids,
    float* __restrict__ out_q, float* __restrict__ ws_loss) {
    const int n = blockIdx.x;
    const int tid = threadIdx.x;
    const int g = tid >> 5;
    const int d4 = tid & 31;
    const int p = pad[n];

    float4 q = make_float4(0.f, 0.f, 0.f, 0.f);
    float s = 0.f;
    if (!p) {
        int id = ws_ids[n * NG + g];
        q = ((const float4*)(cb + ((size_t)id * NG + g) * ND))[d4];
        float4 a = ((const float4*)(x + (size_t)n * (NG * ND)))[tid];
        float e0 = q.x - a.x, e1 = q.y - a.y, e2 = q.z - a.z, e3 = q.w - a.w;
        s = e0 * e0 + e1 * e1 + e2 * e2 + e3 * e3;
    }
    ((float4*)(out_q + (size_t)n * (NG * ND)))[tid] = q;

    for (int off = 32; off > 0; off >>= 1) s += __shfl_down(s, off);
    __shared__ float red[4];
    int w = tid >> 6, lane = tid & 63;
    if (lane == 0) red[w] = s;
    __syncthreads();
    if (tid == 0) ws_loss[n] = (red[0] + red[1]) + (red[2] + red[3]);
}

// ---------------------------------------------------------------------------
__global__ __launch_bounds__(256) void final_kernel(
    const int* __restrict__ pad, const float* __restrict__ ws_loss,
    float* __restrict__ out_l) {
    __shared__ float sr[256];
    __shared__ int mr[256];
    const int tid = threadIdx.x;
    float s = 0.f;
    int m = 0;
    for (int i = tid; i < BT; i += 256) {
        s += ws_loss[i];
        m += 1 - pad[i];
    }
    sr[tid] = s;
    mr[tid] = m;
    __syncthreads();
    for (int st = 128; st > 0; st >>= 1) {
        if (tid < st) { sr[tid] += sr[tid + st]; mr[tid] += mr[tid + st]; }
        __syncthreads();
    }
    if (tid == 0) {
        float k = sr[0] / (float)mr[0];
        out_l[0] = k;
        out_l[1] = k;
        out_l[2] = k + k;
    }
}

// ---------------------------------------------------------------------------
extern "C" void kernel_launch(void* const* d_in, const int* in_sizes, int n_in,
                              void* d_out, int out_size, void* d_ws, size_t ws_size,
                              hipStream_t stream) {
    const float* x = (const float*)d_in[0];
    const int* pad = (const int*)d_in[1];
    const float* cb = (const float*)d_in[2];
    float* out = (float*)d_out;
    float* ws = (float*)d_ws;

    float* ws_c2a = ws + OFF_C2A;
    float* ws_c2b = ws + OFF_C2B;
    int* ws_ids = (int*)(ws + OFF_IDS);
    float* ws_loss = ws + OFF_LOSS;
    int* ws_cnt = (int*)(ws + OFF_CNT);
    int* ws_flags = (int*)(ws + OFF_FLAGS);

    hipMemsetAsync(ws_cnt, 0, 4, stream);
    c2_kernel<<<NV * NG / 256, 256, 0, stream>>>(cb, ws_c2a, ws_c2b);
    mfma_gemm<<<(BT / 128) * NG, 256, 0, stream>>>(x, cb, ws_c2b, pad, ws_ids,
                                                   out + OUT_IDS, ws_cnt, ws_flags);
    recheck<<<256, 256, 0, stream>>>(x, pad, cb, ws_c2a, ws_cnt, ws_flags,
                                     ws_ids, out + OUT_IDS);
    gather_kernel<<<BT, 256, 0, stream>>>(x, pad, cb, ws_ids, out + OUT_Q, ws_loss);
    final_kernel<<<1, 256, 0, stream>>>(pad, ws_loss, out + OUT_L);
}

// Round 7
// 181.036 us; speedup vs baseline: 23.5495x; 23.5495x over previous
//
#include <hip/hip_runtime.h>
#include <math.h>

typedef _Float16 f16;
typedef f16 half8 __attribute__((ext_vector_type(8)));
typedef float f32x4 __attribute__((ext_vector_type(4)));

// Problem sizes: B=4, T=2048, G=8, D=128, V=1024
#define BT 8192
#define NG 8
#define ND 128
#define NV 1024
#define MARGIN 0.02f

// d_out layout (float32): ids[65536] | quantized_st[8388608] | 3 losses
#define OUT_IDS 0
#define OUT_Q   65536
#define OUT_L   (65536 + 8388608)

// ws float offsets (~0.6 MB)
#define OFF_C2A   0          // c2 [v*8+g] (recheck layout)      (8192)
#define OFF_C2B   8192       // c2 [g*NV+v] (gemm layout)        (8192)
#define OFF_IDS   16384      // ids int                          (65536)
#define OFF_LOSS  81920      // per-token loss                   (8192)
#define OFF_CNT   90112      // flag count                       (8)
#define OFF_FLAGS 90120      // flag list                        (65536)

// ---------------------------------------------------------------------------
// c2: both layouts. Arithmetic identical to R1 (pairwise-8 accs, mul+add).
// ---------------------------------------------------------------------------
__global__ __launch_bounds__(256) void c2_kernel(const float* __restrict__ cb,
                                                 float* __restrict__ c2a,
                                                 float* __restrict__ c2b) {
    int idx = blockIdx.x * 256 + threadIdx.x;   // idx = v*8+g
    int v = idx >> 3, g = idx & 7;
    const float* row = cb + (size_t)idx * ND;
    float r[8];
#pragma unroll
    for (int j = 0; j < 8; ++j) r[j] = 0.0f;
#pragma unroll
    for (int k = 0; k < 16; ++k)
#pragma unroll
        for (int j = 0; j < 8; ++j) {
            float c = row[k * 8 + j];
            r[j] = __fadd_rn(r[j], __fmul_rn(c, c));
        }
    float s = __fadd_rn(
        __fadd_rn(__fadd_rn(r[0], r[1]), __fadd_rn(r[2], r[3])),
        __fadd_rn(__fadd_rn(r[4], r[5]), __fadd_rn(r[6], r[7])));
    c2a[idx] = s;
    c2b[g * NV + v] = s;
}

// ---------------------------------------------------------------------------
// MFMA distance GEMM, A-resident: block = 128 tokens x one g, loops 8 code
// tiles. A read once (fp32->fp16 split in regs); B staged per tile from
// L2-resident fp32 cb (split during staging, XOR-swizzled LDS).
// s = xh*ch + xl*ch + xh*cl (3 chained mfma_f32_16x16x32_f16); d' = c2-2s.
// Cross-tile merge (R4-proven): running d1/id + winner-tile margin count
// wcnt + second-best tile-min d2t. Flag iff wcnt>=2 || d2t-d1 < MARGIN.
// Sound: in-winner-tile near-tie -> wcnt>=2; cross-tile near-tie -> its
// tile-min <= that distance < d1+MARGIN -> d2t triggers.
// ---------------------------------------------------------------------------
__global__ __launch_bounds__(256, 2) void mfma_gemm(
    const float* __restrict__ x, const float* __restrict__ cb,
    const float* __restrict__ c2b, const int* __restrict__ pad,
    int* __restrict__ ws_ids, float* __restrict__ out_ids,
    int* __restrict__ cnt, int* __restrict__ flags) {
    __shared__ f16 Bh[128 * 128];
    __shared__ f16 Bl[128 * 128];

    const int tid = threadIdx.x;
    const int b = blockIdx.x;
    const int g = b & 7;
    const int tt = b >> 3;
    const int tok0 = tt * 128;
    const int lane = tid & 63;
    const int w = tid >> 6;
    const int l15 = lane & 15, l4 = lane >> 4;

    // ---- A: load fp32 once, split to fp16 h/l in registers ----
    half8 ah[4][2], al[4][2];   // [kk][ti]
#pragma unroll
    for (int kk = 0; kk < 4; ++kk)
#pragma unroll
        for (int ti = 0; ti < 2; ++ti) {
            const float* ap = x + ((size_t)(tok0 + w * 32 + ti * 16 + l15) * NG + g) * ND
                              + kk * 32 + l4 * 8;
            float4 p0 = *(const float4*)ap, p1 = *(const float4*)(ap + 4);
            float v[8] = {p0.x, p0.y, p0.z, p0.w, p1.x, p1.y, p1.z, p1.w};
            half8 h, l;
#pragma unroll
            for (int j = 0; j < 8; ++j) {
                f16 hh = (f16)v[j];
                h[j] = hh;
                l[j] = (f16)(v[j] - (float)hh);
            }
            ah[kk][ti] = h;
            al[kk][ti] = l;
        }

    float d1r[2][4], d2tr[2][4];
    int idr[2][4], wcntr[2][4];
#pragma unroll
    for (int ti = 0; ti < 2; ++ti)
#pragma unroll
        for (int r = 0; r < 4; ++r) {
            d1r[ti][r] = INFINITY;
            d2tr[ti][r] = INFINITY;
            idr[ti][r] = 0;
            wcntr[ti][r] = 0;
        }

#pragma unroll 1
    for (int cn = 0; cn < 8; ++cn) {
        const int vb0 = cn * 128;
        __syncthreads();
        // stage B tile: fp32 from L2, split + swizzle ((k16 ^ row&7) half8 slots)
#pragma unroll
        for (int i = 0; i < 8; ++i) {
            int s = i * 256 + tid;
            int row = s >> 4, k16 = s & 15;
            const float* cp = cb + ((size_t)(vb0 + row) * NG + g) * ND + k16 * 8;
            float4 q0 = *(const float4*)cp, q1 = *(const float4*)(cp + 4);
            float v[8] = {q0.x, q0.y, q0.z, q0.w, q1.x, q1.y, q1.z, q1.w};
            half8 h, l;
#pragma unroll
            for (int j = 0; j < 8; ++j) {
                f16 hh = (f16)v[j];
                h[j] = hh;
                l[j] = (f16)(v[j] - (float)hh);
            }
            int lo = row * 128 + ((k16 ^ (row & 7)) << 3);
            *(half8*)&Bh[lo] = h;
            *(half8*)&Bl[lo] = l;
        }
        float c2r[8];
#pragma unroll
        for (int tj = 0; tj < 8; ++tj)
            c2r[tj] = c2b[(size_t)g * NV + vb0 + tj * 16 + l15];
        __syncthreads();

        f32x4 acc[2][8];
#pragma unroll
        for (int ti = 0; ti < 2; ++ti)
#pragma unroll
            for (int tj = 0; tj < 8; ++tj) acc[ti][tj] = (f32x4){0.f, 0.f, 0.f, 0.f};

#pragma unroll
        for (int kk = 0; kk < 4; ++kk) {
            {
                half8 bh[8];
#pragma unroll
                for (int tj = 0; tj < 8; ++tj) {
                    int rw = tj * 16 + l15;
                    bh[tj] = *(half8*)&Bh[rw * 128 + (((kk * 4 + l4) ^ (rw & 7)) << 3)];
                }
#pragma unroll
                for (int ti = 0; ti < 2; ++ti)
#pragma unroll
                    for (int tj = 0; tj < 8; ++tj)
                        acc[ti][tj] = __builtin_amdgcn_mfma_f32_16x16x32_f16(
                            ah[kk][ti], bh[tj], acc[ti][tj], 0, 0, 0);
#pragma unroll
                for (int ti = 0; ti < 2; ++ti)
#pragma unroll
                    for (int tj = 0; tj < 8; ++tj)
                        acc[ti][tj] = __builtin_amdgcn_mfma_f32_16x16x32_f16(
                            al[kk][ti], bh[tj], acc[ti][tj], 0, 0, 0);
            }
            {
                half8 bl[8];
#pragma unroll
                for (int tj = 0; tj < 8; ++tj) {
                    int rw = tj * 16 + l15;
                    bl[tj] = *(half8*)&Bl[rw * 128 + (((kk * 4 + l4) ^ (rw & 7)) << 3)];
                }
#pragma unroll
                for (int ti = 0; ti < 2; ++ti)
#pragma unroll
                    for (int tj = 0; tj < 8; ++tj)
                        acc[ti][tj] = __builtin_amdgcn_mfma_f32_16x16x32_f16(
                            ah[kk][ti], bl[tj], acc[ti][tj], 0, 0, 0);
            }
        }

        // epilogue: d' = c2 - 2s; in-wave argmin + tile margin count; merge
#pragma unroll
        for (int ti = 0; ti < 2; ++ti) {
#pragma unroll
            for (int r = 0; r < 4; ++r) {
                float d[8];
#pragma unroll
                for (int tj = 0; tj < 8; ++tj)
                    d[tj] = fmaf(-2.0f, acc[ti][tj][r], c2r[tj]);
                float d1 = d[0];
                int id = vb0 + l15;
#pragma unroll
                for (int tj = 1; tj < 8; ++tj)
                    if (d[tj] < d1) { d1 = d[tj]; id = vb0 + tj * 16 + l15; }
#pragma unroll
                for (int m = 1; m < 16; m <<= 1) {
                    float od = __shfl_xor(d1, m);
                    int oid = __shfl_xor(id, m);
                    if (od < d1) { d1 = od; id = oid; }
                }
                float thr = d1 + MARGIN;
                int cl = 0;
#pragma unroll
                for (int tj = 0; tj < 8; ++tj) cl += (d[tj] < thr) ? 1 : 0;
#pragma unroll
                for (int m = 1; m < 16; m <<= 1) cl += __shfl_xor(cl, m);
                // cross-tile merge (R4 semantics, in registers)
                if (d1 < d1r[ti][r]) {
                    d2tr[ti][r] = d1r[ti][r];
                    d1r[ti][r] = d1;
                    idr[ti][r] = id;
                    wcntr[ti][r] = cl;
                } else {
                    d2tr[ti][r] = fminf(d2tr[ti][r], d1);
                }
            }
        }
    }

    // write ids + flags (lane group leader per token)
    if (l15 == 0) {
#pragma unroll
        for (int ti = 0; ti < 2; ++ti)
#pragma unroll
            for (int r = 0; r < 4; ++r) {
                int tok = tok0 + w * 32 + ti * 16 + l4 * 4 + r;
                int idx = tok * NG + g;
                int id = idr[ti][r];
                ws_ids[idx] = id;
                out_ids[idx] = pad[tok] ? -1.0f : (float)id;
                if (wcntr[ti][r] >= 2 || d2tr[ti][r] - d1r[ti][r] < MARGIN) {
                    int pos = atomicAdd(cnt, 1);
                    flags[pos] = idx;
                }
            }
    }
}

// ---------------------------------------------------------------------------
// exact fp32 recheck for flagged (token,g): R1-identical arithmetic,
// including in-place x2 with the exact pairwise-8 order.
// ---------------------------------------------------------------------------
__global__ __launch_bounds__(256, 1) void recheck(
    const float* __restrict__ x, const int* __restrict__ pad,
    const float* __restrict__ cb, const float* __restrict__ c2w,
    const int* __restrict__ cnt, const int* __restrict__ flags,
    int* __restrict__ ws_ids, float* __restrict__ out_ids) {
    const int lane = threadIdx.x & 63;
    const int wid = (blockIdx.x * 256 + threadIdx.x) >> 6;
    const int nw = gridDim.x * 4;
    const int n_f = cnt[0];
    for (int f = wid; f < n_f; f += nw) {
        int idx = flags[f];
        int g = idx & 7;
        const float4* xr = (const float4*)(x + (size_t)idx * ND);
        float4 xv[32];
#pragma unroll
        for (int i = 0; i < 32; ++i) xv[i] = xr[i];
        // exact x2 (R1 order)
        float rr[8];
#pragma unroll
        for (int j = 0; j < 8; ++j) rr[j] = 0.0f;
#pragma unroll
        for (int i = 0; i < 32; ++i) {
            int j0 = (i * 4) & 7;
            rr[j0 + 0] = __fadd_rn(rr[j0 + 0], __fmul_rn(xv[i].x, xv[i].x));
            rr[j0 + 1] = __fadd_rn(rr[j0 + 1], __fmul_rn(xv[i].y, xv[i].y));
            rr[j0 + 2] = __fadd_rn(rr[j0 + 2], __fmul_rn(xv[i].z, xv[i].z));
            rr[j0 + 3] = __fadd_rn(rr[j0 + 3], __fmul_rn(xv[i].w, xv[i].w));
        }
        float x2v = __fadd_rn(
            __fadd_rn(__fadd_rn(rr[0], rr[1]), __fadd_rn(rr[2], rr[3])),
            __fadd_rn(__fadd_rn(rr[4], rr[5]), __fadd_rn(rr[6], rr[7])));
        float best = INFINITY;
        int bid = 0;
        for (int j = 0; j < 16; ++j) {
            int c = lane + 64 * j;
            const float4* cr = (const float4*)(cb + ((size_t)c * NG + g) * ND);
            float s = 0.f;
#pragma unroll
            for (int i = 0; i < 32; ++i) {
                float4 q = cr[i];
                s = fmaf(xv[i].x, q.x, s);
                s = fmaf(xv[i].y, q.y, s);
                s = fmaf(xv[i].z, q.z, s);
                s = fmaf(xv[i].w, q.w, s);
            }
            float d = __fadd_rn(__fsub_rn(x2v, __fmul_rn(2.0f, s)),
                                c2w[(size_t)c * NG + g]);
            if (d < best) { best = d; bid = c; }
        }
#pragma unroll
        for (int m = 1; m < 64; m <<= 1) {
            float od = __shfl_xor(best, m);
            int ob = __shfl_xor(bid, m);
            if (od < best || (od == best && ob < bid)) { best = od; bid = ob; }
        }
        if (lane == 0) {
            ws_ids[idx] = bid;
            out_ids[idx] = pad[idx >> 3] ? -1.0f : (float)bid;
        }
    }
}

// ---------------------------------------------------------------------------
// gather quantized (masked), write quantized_st, per-token loss partial
// ---------------------------------------------------------------------------
__global__ __launch_bounds__(256) void gather_kernel(
    const float* __restrict__ x, const int* __restrict__ pad,
    const float* __restrict__ cb, const int* __restrict__ ws_ids,
    float* __restrict__ out_q, float* __restrict__ ws_loss) {
    const int n = blockIdx.x;
    const int tid = threadIdx.x;
    const int g = tid >> 5;
    const int d4 = tid & 31;
    const int p = pad[n];

    float4 q = make_float4(0.f, 0.f, 0.f, 0.f);
    float s = 0.f;
    if (!p) {
        int id = ws_ids[n * NG + g];
        q = ((const float4*)(cb + ((size_t)id * NG + g) * ND))[d4];
        float4 a = ((const float4*)(x + (size_t)n * (NG * ND)))[tid];
        float e0 = q.x - a.x, e1 = q.y - a.y, e2 = q.z - a.z, e3 = q.w - a.w;
        s = e0 * e0 + e1 * e1 + e2 * e2 + e3 * e3;
    }
    ((float4*)(out_q + (size_t)n * (NG * ND)))[tid] = q;

    for (int off = 32; off > 0; off >>= 1) s += __shfl_down(s, off);
    __shared__ float red[4];
    int w = tid >> 6, lane = tid & 63;
    if (lane == 0) red[w] = s;
    __syncthreads();
    if (tid == 0) ws_loss[n] = (red[0] + red[1]) + (red[2] + red[3]);
}

// ---------------------------------------------------------------------------
__global__ __launch_bounds__(256) void final_kernel(
    const int* __restrict__ pad, const float* __restrict__ ws_loss,
    float* __restrict__ out_l) {
    __shared__ float sr[256];
    __shared__ int mr[256];
    const int tid = threadIdx.x;
    float s = 0.f;
    int m = 0;
    for (int i = tid; i < BT; i += 256) {
        s += ws_loss[i];
        m += 1 - pad[i];
    }
    sr[tid] = s;
    mr[tid] = m;
    __syncthreads();
    for (int st = 128; st > 0; st >>= 1) {
        if (tid < st) { sr[tid] += sr[tid + st]; mr[tid] += mr[tid + st]; }
        __syncthreads();
    }
    if (tid == 0) {
        float k = sr[0] / (float)mr[0];
        out_l[0] = k;
        out_l[1] = k;
        out_l[2] = k + k;
    }
}

// ---------------------------------------------------------------------------
extern "C" void kernel_launch(void* const* d_in, const int* in_sizes, int n_in,
                              void* d_out, int out_size, void* d_ws, size_t ws_size,
                              hipStream_t stream) {
    const float* x = (const float*)d_in[0];
    const int* pad = (const int*)d_in[1];
    const float* cb = (const float*)d_in[2];
    float* out = (float*)d_out;
    float* ws = (float*)d_ws;

    float* ws_c2a = ws + OFF_C2A;
    float* ws_c2b = ws + OFF_C2B;
    int* ws_ids = (int*)(ws + OFF_IDS);
    float* ws_loss = ws + OFF_LOSS;
    int* ws_cnt = (int*)(ws + OFF_CNT);
    int* ws_flags = (int*)(ws + OFF_FLAGS);

    hipMemsetAsync(ws_cnt, 0, 4, stream);
    c2_kernel<<<NV * NG / 256, 256, 0, stream>>>(cb, ws_c2a, ws_c2b);
    mfma_gemm<<<(BT / 128) * NG, 256, 0, stream>>>(x, cb, ws_c2b, pad, ws_ids,
                                                   out + OUT_IDS, ws_cnt, ws_flags);
    recheck<<<256, 256, 0, stream>>>(x, pad, cb, ws_c2a, ws_cnt, ws_flags,
                                     ws_ids, out + OUT_IDS);
    gather_kernel<<<BT, 256, 0, stream>>>(x, pad, cb, ws_ids, out + OUT_Q, ws_loss);
    final_kernel<<<1, 256, 0, stream>>>(pad, ws_loss, out + OUT_L);
}

// Round 8
// 161.390 us; speedup vs baseline: 26.4161x; 1.1217x over previous
//
#include <hip/hip_runtime.h>
#include <math.h>

typedef _Float16 f16;
typedef f16 half8 __attribute__((ext_vector_type(8)));
typedef float f32x4 __attribute__((ext_vector_type(4)));

// Problem sizes: B=4, T=2048, G=8, D=128, V=1024
#define BT 8192
#define NG 8
#define ND 128
#define NV 1024
#define MARGIN 0.02f
#define BM 128       // tokens per block
#define BN 64        // codes per tile
#define NT 16        // code tiles

// d_out layout (float32): ids[65536] | quantized_st[8388608] | 3 losses
#define OUT_IDS 0
#define OUT_Q   65536
#define OUT_L   (65536 + 8388608)

// ws float offsets (~4.8 MB)
#define OFF_C2A   0                        // c2 [v*8+g] (recheck)     (8192)
#define OFF_C2B   8192                     // c2 [g*NV+v] (gemm)       (8192)
#define OFF_IDS   16384                    // ids int                  (65536)
#define OFF_LOSS  81920                    // per-token loss           (8192)
#define OFF_CNT   90112                    // flag count               (8)
#define OFF_FLAGS 90120                    // flag list                (65536)
#define OFF_CBH   155656                   // cbh fp16 swizzled stream (524288 fl)
#define OFF_CBL   (OFF_CBH + 524288)       // cbl fp16 swizzled stream (524288 fl)

// ---------------------------------------------------------------------------
// async global->LDS, 16B per lane (linear dest, pre-swizzled source)
// ---------------------------------------------------------------------------
__device__ __forceinline__ void gll16(const f16* g, f16* l) {
    __builtin_amdgcn_global_load_lds(
        (const __attribute__((address_space(1))) unsigned int*)g,
        (__attribute__((address_space(3))) unsigned int*)l, 16, 0, 0);
}

// ---------------------------------------------------------------------------
// prep: c2 (both layouts, R1-exact pairwise-8 order) + fp16 h/l split of the
// codebook written as PRE-SWIZZLED g-blocked streams (LDS-linear order):
// stream[(g*16+cn)*8192 + row*128 + j*8 + e] = cb[v=cn*64+row][(j^(row&7))*8+e]
// so a linear global_load_lds fill yields the XOR-swizzled LDS tile.
// ---------------------------------------------------------------------------
__global__ __launch_bounds__(256) void prep_kernel(
    const float* __restrict__ cb, f16* __restrict__ cbh, f16* __restrict__ cbl,
    float* __restrict__ c2a, float* __restrict__ c2b, int* __restrict__ cnt) {
    int idx = blockIdx.x * 256 + threadIdx.x;   // v*8+g
    if (idx == 0) *cnt = 0;
    int v = idx >> 3, g = idx & 7;
    const float* row = cb + (size_t)idx * ND;

    float r[8];
#pragma unroll
    for (int j = 0; j < 8; ++j) r[j] = 0.0f;
#pragma unroll
    for (int k = 0; k < 16; ++k)
#pragma unroll
        for (int j = 0; j < 8; ++j) {
            float c = row[k * 8 + j];
            r[j] = __fadd_rn(r[j], __fmul_rn(c, c));
        }
    float s = __fadd_rn(
        __fadd_rn(__fadd_rn(r[0], r[1]), __fadd_rn(r[2], r[3])),
        __fadd_rn(__fadd_rn(r[4], r[5]), __fadd_rn(r[6], r[7])));
    c2a[idx] = s;
    c2b[g * NV + v] = s;

    int cn = v >> 6, rl = v & 63;
    size_t base = ((size_t)(g * 16 + cn)) * 8192 + rl * 128;
#pragma unroll
    for (int j = 0; j < 16; ++j) {
        int js = (j ^ (rl & 7)) * 8;
        half8 h, l;
#pragma unroll
        for (int e = 0; e < 8; ++e) {
            float vv = row[js + e];
            f16 hh = (f16)vv;
            h[e] = hh;
            l[e] = (f16)(vv - (float)hh);
        }
        *(half8*)(cbh + base + j * 8) = h;
        *(half8*)(cbl + base + j * 8) = l;
    }
}

// ---------------------------------------------------------------------------
// MFMA distance GEMM. Block = 128 tokens x one g; 4 waves = 2 token-halves
// (wr) x 2 code-halves (wc); wave = 64 tokens x 32 codes per tile. A fp32
// read once, fp16-split in regs (128 VGPR). B: 16 tiles of 64 codes, double-
// buffered LDS filled by async global_load_lds from the pre-swizzled stream
// (1 barrier/tile). s = xh*ch + xh*cl + xl*ch; d' = c2 - 2s (x2 cancels).
// Per-thread running top-2 across ALL tiles; one merge at the end.
// Flag iff d2 - d1 < MARGIN  => exact recheck (sound).
// ---------------------------------------------------------------------------
__global__ __launch_bounds__(256, 2) void mfma_gemm(
    const float* __restrict__ x, const f16* __restrict__ cbh,
    const f16* __restrict__ cbl, const float* __restrict__ c2b,
    const int* __restrict__ pad, int* __restrict__ ws_ids,
    float* __restrict__ out_ids, int* __restrict__ cnt,
    int* __restrict__ flags) {
    __shared__ __align__(16) f16 Bh[2][BN * ND];   // 2 x 16 KB
    __shared__ __align__(16) f16 Bl[2][BN * ND];   // 2 x 16 KB

    const int tid = threadIdx.x;
    const int b = blockIdx.x;
    const int g = b & 7;
    const int tok0 = (b >> 3) * BM;
    const int lane = tid & 63;
    const int w = tid >> 6;
    const int wr = w & 1, wc = w >> 1;
    const int l15 = lane & 15, l4 = lane >> 4;

    // ---- A: load fp32 once, split to fp16 h/l in registers (64 tokens) ----
    half8 ah[4][4], al[4][4];   // [kk][ti]
#pragma unroll
    for (int kk = 0; kk < 4; ++kk)
#pragma unroll
        for (int ti = 0; ti < 4; ++ti) {
            const float* ap = x + ((size_t)(tok0 + wr * 64 + ti * 16 + l15) * NG + g) * ND
                              + kk * 32 + l4 * 8;
            float4 p0 = *(const float4*)ap, p1 = *(const float4*)(ap + 4);
            float v[8] = {p0.x, p0.y, p0.z, p0.w, p1.x, p1.y, p1.z, p1.w};
            half8 h, l;
#pragma unroll
            for (int j = 0; j < 8; ++j) {
                f16 hh = (f16)v[j];
                h[j] = hh;
                l[j] = (f16)(v[j] - (float)hh);
            }
            ah[kk][ti] = h;
            al[kk][ti] = l;
        }

    float d1s[4][4], d2s[4][4];
    int ids_[4][4];
#pragma unroll
    for (int ti = 0; ti < 4; ++ti)
#pragma unroll
        for (int r = 0; r < 4; ++r) {
            d1s[ti][r] = INFINITY;
            d2s[ti][r] = INFINITY;
            ids_[ti][r] = 0;
        }

    // prologue: stage tile 0 into buffer 0
    {
        const f16* sh = cbh + ((size_t)(g * 16 + 0)) * 8192;
        const f16* sl = cbl + ((size_t)(g * 16 + 0)) * 8192;
#pragma unroll
        for (int it = 0; it < 4; ++it) {
            int off = it * 2048 + tid * 8;
            gll16(sh + off, &Bh[0][off]);
            gll16(sl + off, &Bl[0][off]);
        }
    }
    __syncthreads();

    int buf = 0;
#pragma unroll 1
    for (int cn = 0; cn < NT; ++cn) {
        const int vb0 = cn * BN;
        // async prefetch next tile into the other buffer
        if (cn + 1 < NT) {
            const f16* sh = cbh + ((size_t)(g * 16 + cn + 1)) * 8192;
            const f16* sl = cbl + ((size_t)(g * 16 + cn + 1)) * 8192;
#pragma unroll
            for (int it = 0; it < 4; ++it) {
                int off = it * 2048 + tid * 8;
                gll16(sh + off, &Bh[buf ^ 1][off]);
                gll16(sl + off, &Bl[buf ^ 1][off]);
            }
        }
        float c2r[2];
#pragma unroll
        for (int tj = 0; tj < 2; ++tj)
            c2r[tj] = c2b[(size_t)g * NV + vb0 + wc * 32 + tj * 16 + l15];

        const f16* bhp = &Bh[buf][0];
        const f16* blp = &Bl[buf][0];
        f32x4 acc[4][2];
#pragma unroll
        for (int ti = 0; ti < 4; ++ti)
#pragma unroll
            for (int tj = 0; tj < 2; ++tj) acc[ti][tj] = (f32x4){0.f, 0.f, 0.f, 0.f};

#pragma unroll
        for (int kk = 0; kk < 4; ++kk) {
            half8 bh[2], bl[2];
#pragma unroll
            for (int tj = 0; tj < 2; ++tj) {
                int rw = wc * 32 + tj * 16 + l15;
                int off = rw * 128 + (((kk * 4 + l4) ^ (rw & 7)) << 3);
                bh[tj] = *(const half8*)(bhp + off);
                bl[tj] = *(const half8*)(blp + off);
            }
#pragma unroll
            for (int ti = 0; ti < 4; ++ti)
#pragma unroll
                for (int tj = 0; tj < 2; ++tj)
                    acc[ti][tj] = __builtin_amdgcn_mfma_f32_16x16x32_f16(
                        ah[kk][ti], bh[tj], acc[ti][tj], 0, 0, 0);
#pragma unroll
            for (int ti = 0; ti < 4; ++ti)
#pragma unroll
                for (int tj = 0; tj < 2; ++tj)
                    acc[ti][tj] = __builtin_amdgcn_mfma_f32_16x16x32_f16(
                        ah[kk][ti], bl[tj], acc[ti][tj], 0, 0, 0);
#pragma unroll
            for (int ti = 0; ti < 4; ++ti)
#pragma unroll
                for (int tj = 0; tj < 2; ++tj)
                    acc[ti][tj] = __builtin_amdgcn_mfma_f32_16x16x32_f16(
                        al[kk][ti], bh[tj], acc[ti][tj], 0, 0, 0);
        }

        // epilogue: per-thread running top-2 (no cross-lane work per tile)
#pragma unroll
        for (int ti = 0; ti < 4; ++ti)
#pragma unroll
            for (int r = 0; r < 4; ++r)
#pragma unroll
                for (int tj = 0; tj < 2; ++tj) {
                    float dv = fmaf(-2.0f, acc[ti][tj][r], c2r[tj]);
                    int c = vb0 + wc * 32 + tj * 16 + l15;
                    if (dv < d1s[ti][r]) {
                        d2s[ti][r] = d1s[ti][r];
                        d1s[ti][r] = dv;
                        ids_[ti][r] = c;
                    } else {
                        d2s[ti][r] = fminf(d2s[ti][r], dv);
                    }
                }

        __syncthreads();   // drains prefetch vmcnt + all waves done with buf
        buf ^= 1;
    }

    // final merge: 4 xor-shuffle stages across l15, then across wc via LDS
    float4* red = (float4*)&Bh[0][0];   // overlay (Bh free after last barrier)
#pragma unroll
    for (int ti = 0; ti < 4; ++ti)
#pragma unroll
        for (int r = 0; r < 4; ++r) {
            float d1 = d1s[ti][r], d2 = d2s[ti][r];
            int id = ids_[ti][r];
#pragma unroll
            for (int m = 1; m < 16; m <<= 1) {
                float od1 = __shfl_xor(d1, m);
                float od2 = __shfl_xor(d2, m);
                int oid = __shfl_xor(id, m);
                if (od1 < d1) { d2 = fminf(d1, od2); d1 = od1; id = oid; }
                else d2 = fminf(d2, fminf(od1, od2));
            }
            if (l15 == 0)
                red[wc * BM + wr * 64 + ti * 16 + l4 * 4 + r] =
                    make_float4(d1, __int_as_float(id), d2, 0.f);
        }
    __syncthreads();

    if (tid < BM) {
        float4 a = red[tid], c = red[BM + tid];
        float d1 = a.x, d2 = a.z;
        int id = __float_as_int(a.y);
        if (c.x < d1) { d2 = fminf(d1, c.z); d1 = c.x; id = __float_as_int(c.y); }
        else d2 = fminf(d2, fminf(c.x, c.z));
        int tok = tok0 + tid;
        int idx = tok * NG + g;
        ws_ids[idx] = id;
        out_ids[idx] = pad[tok] ? -1.0f : (float)id;
        if (d2 - d1 < MARGIN) {
            int pos = atomicAdd(cnt, 1);
            flags[pos] = idx;
        }
    }
}

// ---------------------------------------------------------------------------
// exact fp32 recheck for flagged (token,g): R1-identical arithmetic.
// ---------------------------------------------------------------------------
__global__ __launch_bounds__(256, 1) void recheck(
    const float* __restrict__ x, const int* __restrict__ pad,
    const float* __restrict__ cb, const float* __restrict__ c2w,
    const int* __restrict__ cnt, const int* __restrict__ flags,
    int* __restrict__ ws_ids, float* __restrict__ out_ids) {
    const int lane = threadIdx.x & 63;
    const int wid = (blockIdx.x * 256 + threadIdx.x) >> 6;
    const int nw = gridDim.x * 4;
    const int n_f = cnt[0];
    for (int f = wid; f < n_f; f += nw) {
        int idx = flags[f];
        int g = idx & 7;
        const float4* xr = (const float4*)(x + (size_t)idx * ND);
        float4 xv[32];
#pragma unroll
        for (int i = 0; i < 32; ++i) xv[i] = xr[i];
        float rr[8];
#pragma unroll
        for (int j = 0; j < 8; ++j) rr[j] = 0.0f;
#pragma unroll
        for (int i = 0; i < 32; ++i) {
            int j0 = (i * 4) & 7;
            rr[j0 + 0] = __fadd_rn(rr[j0 + 0], __fmul_rn(xv[i].x, xv[i].x));
            rr[j0 + 1] = __fadd_rn(rr[j0 + 1], __fmul_rn(xv[i].y, xv[i].y));
            rr[j0 + 2] = __fadd_rn(rr[j0 + 2], __fmul_rn(xv[i].z, xv[i].z));
            rr[j0 + 3] = __fadd_rn(rr[j0 + 3], __fmul_rn(xv[i].w, xv[i].w));
        }
        float x2v = __fadd_rn(
            __fadd_rn(__fadd_rn(rr[0], rr[1]), __fadd_rn(rr[2], rr[3])),
            __fadd_rn(__fadd_rn(rr[4], rr[5]), __fadd_rn(rr[6], rr[7])));
        float best = INFINITY;
        int bid = 0;
        for (int j = 0; j < 16; ++j) {
            int c = lane + 64 * j;
            const float4* cr = (const float4*)(cb + ((size_t)c * NG + g) * ND);
            float s = 0.f;
#pragma unroll
            for (int i = 0; i < 32; ++i) {
                float4 q = cr[i];
                s = fmaf(xv[i].x, q.x, s);
                s = fmaf(xv[i].y, q.y, s);
                s = fmaf(xv[i].z, q.z, s);
                s = fmaf(xv[i].w, q.w, s);
            }
            float d = __fadd_rn(__fsub_rn(x2v, __fmul_rn(2.0f, s)),
                                c2w[(size_t)c * NG + g]);
            if (d < best) { best = d; bid = c; }
        }
#pragma unroll
        for (int m = 1; m < 64; m <<= 1) {
            float od = __shfl_xor(best, m);
            int ob = __shfl_xor(bid, m);
            if (od < best || (od == best && ob < bid)) { best = od; bid = ob; }
        }
        if (lane == 0) {
            ws_ids[idx] = bid;
            out_ids[idx] = pad[idx >> 3] ? -1.0f : (float)bid;
        }
    }
}

// ---------------------------------------------------------------------------
// gather quantized (masked), write quantized_st, per-token loss partial
// ---------------------------------------------------------------------------
__global__ __launch_bounds__(256) void gather_kernel(
    const float* __restrict__ x, const int* __restrict__ pad,
    const float* __restrict__ cb, const int* __restrict__ ws_ids,
    float* __restrict__ out_q, float* __restrict__ ws_loss) {
    const int n = blockIdx.x;
    const int tid = threadIdx.x;
    const int g = tid >> 5;
    const int d4 = tid & 31;
    const int p = pad[n];

    float4 q = make_float4(0.f, 0.f, 0.f, 0.f);
    float s = 0.f;
    if (!p) {
        int id = ws_ids[n * NG + g];
        q = ((const float4*)(cb + ((size_t)id * NG + g) * ND))[d4];
        float4 a = ((const float4*)(x + (size_t)n * (NG * ND)))[tid];
        float e0 = q.x - a.x, e1 = q.y - a.y, e2 = q.z - a.z, e3 = q.w - a.w;
        s = e0 * e0 + e1 * e1 + e2 * e2 + e3 * e3;
    }
    ((float4*)(out_q + (size_t)n * (NG * ND)))[tid] = q;

    for (int off = 32; off > 0; off >>= 1) s += __shfl_down(s, off);
    __shared__ float red[4];
    int w = tid >> 6, lane = tid & 63;
    if (lane == 0) red[w] = s;
    __syncthreads();
    if (tid == 0) ws_loss[n] = (red[0] + red[1]) + (red[2] + red[3]);
}

// ---------------------------------------------------------------------------
__global__ __launch_bounds__(256) void final_kernel(
    const int* __restrict__ pad, const float* __restrict__ ws_loss,
    float* __restrict__ out_l) {
    __shared__ float sr[256];
    __shared__ int mr[256];
    const int tid = threadIdx.x;
    float s = 0.f;
    int m = 0;
    for (int i = tid; i < BT; i += 256) {
        s += ws_loss[i];
        m += 1 - pad[i];
    }
    sr[tid] = s;
    mr[tid] = m;
    __syncthreads();
    for (int st = 128; st > 0; st >>= 1) {
        if (tid < st) { sr[tid] += sr[tid + st]; mr[tid] += mr[tid + st]; }
        __syncthreads();
    }
    if (tid == 0) {
        float k = sr[0] / (float)mr[0];
        out_l[0] = k;
        out_l[1] = k;
        out_l[2] = k + k;
    }
}

// ---------------------------------------------------------------------------
extern "C" void kernel_launch(void* const* d_in, const int* in_sizes, int n_in,
                              void* d_out, int out_size, void* d_ws, size_t ws_size,
                              hipStream_t stream) {
    const float* x = (const float*)d_in[0];
    const int* pad = (const int*)d_in[1];
    const float* cb = (const float*)d_in[2];
    float* out = (float*)d_out;
    float* ws = (float*)d_ws;

    float* ws_c2a = ws + OFF_C2A;
    float* ws_c2b = ws + OFF_C2B;
    int* ws_ids = (int*)(ws + OFF_IDS);
    float* ws_loss = ws + OFF_LOSS;
    int* ws_cnt = (int*)(ws + OFF_CNT);
    int* ws_flags = (int*)(ws + OFF_FLAGS);
    f16* cbh = (f16*)(ws + OFF_CBH);
    f16* cbl = (f16*)(ws + OFF_CBL);

    prep_kernel<<<NV * NG / 256, 256, 0, stream>>>(cb, cbh, cbl, ws_c2a, ws_c2b,
                                                   ws_cnt);
    mfma_gemm<<<(BT / BM) * NG, 256, 0, stream>>>(x, cbh, cbl, ws_c2b, pad,
                                                  ws_ids, out + OUT_IDS, ws_cnt,
                                                  ws_flags);
    recheck<<<64, 256, 0, stream>>>(x, pad, cb, ws_c2a, ws_cnt, ws_flags,
                                    ws_ids, out + OUT_IDS);
    gather_kernel<<<BT, 256, 0, stream>>>(x, pad, cb, ws_ids, out + OUT_Q, ws_loss);
    final_kernel<<<1, 256, 0, stream>>>(pad, ws_loss, out + OUT_L);
}

// Round 9
// 132.519 us; speedup vs baseline: 32.1713x; 1.2179x over previous
//
#include <hip/hip_runtime.h>
#include <math.h>

typedef _Float16 f16;
typedef f16 half8 __attribute__((ext_vector_type(8)));
typedef float f32x4 __attribute__((ext_vector_type(4)));

// Problem sizes: B=4, T=2048, G=8, D=128, V=1024
#define BT 8192
#define NG 8
#define ND 128
#define NV 1024
#define MARGIN 0.02f
#define BM 64        // tokens per block
#define BN 64        // codes per tile
#define NT 16        // code tiles

// d_out layout (float32): ids[65536] | quantized_st[8388608] | 3 losses
#define OUT_IDS 0
#define OUT_Q   65536
#define OUT_L   (65536 + 8388608)

// ws float offsets (~4.8 MB)
#define OFF_C2A   0                        // c2 [v*8+g] (recheck)     (8192)
#define OFF_C2B   8192                     // c2 [g*NV+v] (gemm)       (8192)
#define OFF_IDS   16384                    // ids int                  (65536)
#define OFF_LOSS  81920                    // per-token loss           (8192)
#define OFF_CNT   90112                    // flag count               (8)
#define OFF_FLAGS 90120                    // flag list                (65536)
#define OFF_CBH   155656                   // cbh fp16 swizzled stream (524288 fl)
#define OFF_CBL   (OFF_CBH + 524288)       // cbl fp16 swizzled stream (524288 fl)

// ---------------------------------------------------------------------------
// async global->LDS, 16B per lane (linear dest, pre-swizzled source)
// ---------------------------------------------------------------------------
__device__ __forceinline__ void gll16(const f16* g, f16* l) {
    __builtin_amdgcn_global_load_lds(
        (const __attribute__((address_space(1))) unsigned int*)g,
        (__attribute__((address_space(3))) unsigned int*)l, 16, 0, 0);
}

// ---------------------------------------------------------------------------
// prep: c2 (both layouts, R1-exact pairwise-8 order) + fp16 h/l split of the
// codebook written as PRE-SWIZZLED g-blocked streams (LDS-linear order):
// stream[(g*16+cn)*8192 + row*128 + j*8 + e] = cb[v=cn*64+row][(j^(row&7))*8+e]
// ---------------------------------------------------------------------------
__global__ __launch_bounds__(256) void prep_kernel(
    const float* __restrict__ cb, f16* __restrict__ cbh, f16* __restrict__ cbl,
    float* __restrict__ c2a, float* __restrict__ c2b, int* __restrict__ cnt) {
    int idx = blockIdx.x * 256 + threadIdx.x;   // v*8+g
    if (idx == 0) *cnt = 0;
    int v = idx >> 3, g = idx & 7;
    const float* row = cb + (size_t)idx * ND;

    float r[8];
#pragma unroll
    for (int j = 0; j < 8; ++j) r[j] = 0.0f;
#pragma unroll
    for (int k = 0; k < 16; ++k)
#pragma unroll
        for (int j = 0; j < 8; ++j) {
            float c = row[k * 8 + j];
            r[j] = __fadd_rn(r[j], __fmul_rn(c, c));
        }
    float s = __fadd_rn(
        __fadd_rn(__fadd_rn(r[0], r[1]), __fadd_rn(r[2], r[3])),
        __fadd_rn(__fadd_rn(r[4], r[5]), __fadd_rn(r[6], r[7])));
    c2a[idx] = s;
    c2b[g * NV + v] = s;

    int cn = v >> 6, rl = v & 63;
    size_t base = ((size_t)(g * 16 + cn)) * 8192 + rl * 128;
#pragma unroll
    for (int j = 0; j < 16; ++j) {
        int js = (j ^ (rl & 7)) * 8;
        half8 h, l;
#pragma unroll
        for (int e = 0; e < 8; ++e) {
            float vv = row[js + e];
            f16 hh = (f16)vv;
            h[e] = hh;
            l[e] = (f16)(vv - (float)hh);
        }
        *(half8*)(cbh + base + j * 8) = h;
        *(half8*)(cbl + base + j * 8) = l;
    }
}

// ---------------------------------------------------------------------------
// MFMA distance GEMM. Block = 64 tokens x one g; 4 waves = 2 token-halves
// (wr) x 2 code-halves (wc); wave = 32 tokens x 32 codes per tile.
// A fp32 read once, fp16-split in regs (64 VGPR). B: 16 tiles of 64 codes,
// single 32KB LDS buffer filled by global_load_lds (2 barriers/tile); 4
// blocks/CU (launch_bounds(256,4), grid 1024) provide TLP to hide staging.
// s = xh*ch + xh*cl + xl*ch; d' = c2 - 2s (x2 cancels in argmin).
// Exact per-thread running top-2 across all tiles; one merge at block end.
// Flag iff d2 - d1 < MARGIN => exact recheck (sound).
// ---------------------------------------------------------------------------
__global__ __launch_bounds__(256, 4) void mfma_gemm(
    const float* __restrict__ x, const f16* __restrict__ cbh,
    const f16* __restrict__ cbl, const float* __restrict__ c2b,
    const int* __restrict__ pad, int* __restrict__ ws_ids,
    float* __restrict__ out_ids, int* __restrict__ cnt,
    int* __restrict__ flags) {
    __shared__ __align__(16) f16 Bh[BN * ND];   // 16 KB
    __shared__ __align__(16) f16 Bl[BN * ND];   // 16 KB

    const int tid = threadIdx.x;
    const int b = blockIdx.x;
    const int g = b & 7;
    const int tok0 = (b >> 3) * BM;
    const int lane = tid & 63;
    const int w = tid >> 6;
    const int wr = w & 1, wc = w >> 1;
    const int l15 = lane & 15, l4 = lane >> 4;

    // ---- A: load fp32 once, split to fp16 h/l in registers (32 tokens) ----
    half8 ah[4][2], al[4][2];   // [kk][ti]
#pragma unroll
    for (int kk = 0; kk < 4; ++kk)
#pragma unroll
        for (int ti = 0; ti < 2; ++ti) {
            const float* ap = x + ((size_t)(tok0 + wr * 32 + ti * 16 + l15) * NG + g) * ND
                              + kk * 32 + l4 * 8;
            float4 p0 = *(const float4*)ap, p1 = *(const float4*)(ap + 4);
            float v[8] = {p0.x, p0.y, p0.z, p0.w, p1.x, p1.y, p1.z, p1.w};
            half8 h, l;
#pragma unroll
            for (int j = 0; j < 8; ++j) {
                f16 hh = (f16)v[j];
                h[j] = hh;
                l[j] = (f16)(v[j] - (float)hh);
            }
            ah[kk][ti] = h;
            al[kk][ti] = l;
        }

    float d1s[2][4], d2s[2][4];
    int ids_[2][4];
#pragma unroll
    for (int ti = 0; ti < 2; ++ti)
#pragma unroll
        for (int r = 0; r < 4; ++r) {
            d1s[ti][r] = INFINITY;
            d2s[ti][r] = INFINITY;
            ids_[ti][r] = 0;
        }

#pragma unroll 1
    for (int cn = 0; cn < NT; ++cn) {
        const int vb0 = cn * BN;
        __syncthreads();                       // prev tile fully consumed
        {
            const f16* sh = cbh + ((size_t)(g * 16 + cn)) * 8192;
            const f16* sl = cbl + ((size_t)(g * 16 + cn)) * 8192;
#pragma unroll
            for (int it = 0; it < 4; ++it) {
                int off = it * 2048 + tid * 8;
                gll16(sh + off, &Bh[off]);
                gll16(sl + off, &Bl[off]);
            }
        }
        float c2r[2];
#pragma unroll
        for (int tj = 0; tj < 2; ++tj)
            c2r[tj] = c2b[(size_t)g * NV + vb0 + wc * 32 + tj * 16 + l15];
        __syncthreads();                       // drains vmcnt -> tile ready

        f32x4 acc[2][2];
#pragma unroll
        for (int ti = 0; ti < 2; ++ti)
#pragma unroll
            for (int tj = 0; tj < 2; ++tj) acc[ti][tj] = (f32x4){0.f, 0.f, 0.f, 0.f};

#pragma unroll
        for (int kk = 0; kk < 4; ++kk) {
            half8 bh[2], bl[2];
#pragma unroll
            for (int tj = 0; tj < 2; ++tj) {
                int rw = wc * 32 + tj * 16 + l15;
                int off = rw * 128 + (((kk * 4 + l4) ^ (rw & 7)) << 3);
                bh[tj] = *(const half8*)(Bh + off);
                bl[tj] = *(const half8*)(Bl + off);
            }
#pragma unroll
            for (int ti = 0; ti < 2; ++ti)
#pragma unroll
                for (int tj = 0; tj < 2; ++tj)
                    acc[ti][tj] = __builtin_amdgcn_mfma_f32_16x16x32_f16(
                        ah[kk][ti], bh[tj], acc[ti][tj], 0, 0, 0);
#pragma unroll
            for (int ti = 0; ti < 2; ++ti)
#pragma unroll
                for (int tj = 0; tj < 2; ++tj)
                    acc[ti][tj] = __builtin_amdgcn_mfma_f32_16x16x32_f16(
                        ah[kk][ti], bl[tj], acc[ti][tj], 0, 0, 0);
#pragma unroll
            for (int ti = 0; ti < 2; ++ti)
#pragma unroll
                for (int tj = 0; tj < 2; ++tj)
                    acc[ti][tj] = __builtin_amdgcn_mfma_f32_16x16x32_f16(
                        al[kk][ti], bh[tj], acc[ti][tj], 0, 0, 0);
        }

        // per-thread running exact top-2
#pragma unroll
        for (int ti = 0; ti < 2; ++ti)
#pragma unroll
            for (int r = 0; r < 4; ++r)
#pragma unroll
                for (int tj = 0; tj < 2; ++tj) {
                    float dv = fmaf(-2.0f, acc[ti][tj][r], c2r[tj]);
                    int c = vb0 + wc * 32 + tj * 16 + l15;
                    if (dv < d1s[ti][r]) {
                        d2s[ti][r] = d1s[ti][r];
                        d1s[ti][r] = dv;
                        ids_[ti][r] = c;
                    } else {
                        d2s[ti][r] = fminf(d2s[ti][r], dv);
                    }
                }
    }

    // final merge: 4 xor-shuffle stages across l15, then across wc via LDS
    __syncthreads();
    float4* red = (float4*)&Bh[0];   // overlay (Bh free after barrier)
#pragma unroll
    for (int ti = 0; ti < 2; ++ti)
#pragma unroll
        for (int r = 0; r < 4; ++r) {
            float d1 = d1s[ti][r], d2 = d2s[ti][r];
            int id = ids_[ti][r];
#pragma unroll
            for (int m = 1; m < 16; m <<= 1) {
                float od1 = __shfl_xor(d1, m);
                float od2 = __shfl_xor(d2, m);
                int oid = __shfl_xor(id, m);
                if (od1 < d1) { d2 = fminf(d1, od2); d1 = od1; id = oid; }
                else d2 = fminf(d2, fminf(od1, od2));
            }
            if (l15 == 0)
                red[wc * BM + wr * 32 + ti * 16 + l4 * 4 + r] =
                    make_float4(d1, __int_as_float(id), d2, 0.f);
        }
    __syncthreads();

    if (tid < BM) {
        float4 a = red[tid], c = red[BM + tid];
        float d1 = a.x, d2 = a.z;
        int id = __float_as_int(a.y);
        if (c.x < d1) { d2 = fminf(d1, c.z); d1 = c.x; id = __float_as_int(c.y); }
        else d2 = fminf(d2, fminf(c.x, c.z));
        int tok = tok0 + tid;
        int idx = tok * NG + g;
        ws_ids[idx] = id;
        out_ids[idx] = pad[tok] ? -1.0f : (float)id;
        if (d2 - d1 < MARGIN) {
            int pos = atomicAdd(cnt, 1);
            flags[pos] = idx;
        }
    }
}

// ---------------------------------------------------------------------------
// exact fp32 recheck, BLOCK per flag: 256 threads, 4 codes/thread (ILP 4),
// x row staged in LDS (broadcast reads). R1-identical per-code arithmetic;
// index tie-break reduce == first-occurrence argmin.
// ---------------------------------------------------------------------------
__global__ __launch_bounds__(256) void recheck(
    const float* __restrict__ x, const int* __restrict__ pad,
    const float* __restrict__ cb, const float* __restrict__ c2w,
    const int* __restrict__ cnt, const int* __restrict__ flags,
    int* __restrict__ ws_ids, float* __restrict__ out_ids) {
    __shared__ __align__(16) float xs[ND];
    __shared__ float2 redw[4];
    const int tid = threadIdx.x;
    const int lane = tid & 63;
    const int w = tid >> 6;
    const int n_f = cnt[0];

    for (int f = blockIdx.x; f < n_f; f += gridDim.x) {
        int idx = flags[f];
        int g = idx & 7;
        __syncthreads();   // previous iteration's reads done
        if (tid < 32)
            ((float4*)xs)[tid] = ((const float4*)(x + (size_t)idx * ND))[tid];
        __syncthreads();

        // exact x2 (R1 pairwise-8 order), redundant per thread (broadcast)
        float rr[8];
#pragma unroll
        for (int j = 0; j < 8; ++j) rr[j] = 0.0f;
#pragma unroll
        for (int i = 0; i < 32; ++i) {
            float4 v = ((const float4*)xs)[i];
            int j0 = (i * 4) & 7;
            rr[j0 + 0] = __fadd_rn(rr[j0 + 0], __fmul_rn(v.x, v.x));
            rr[j0 + 1] = __fadd_rn(rr[j0 + 1], __fmul_rn(v.y, v.y));
            rr[j0 + 2] = __fadd_rn(rr[j0 + 2], __fmul_rn(v.z, v.z));
            rr[j0 + 3] = __fadd_rn(rr[j0 + 3], __fmul_rn(v.w, v.w));
        }
        float x2v = __fadd_rn(
            __fadd_rn(__fadd_rn(rr[0], rr[1]), __fadd_rn(rr[2], rr[3])),
            __fadd_rn(__fadd_rn(rr[4], rr[5]), __fadd_rn(rr[6], rr[7])));

        // 4 codes per thread, independent chains
        float best = INFINITY;
        int bid = 0x7FFFFFFF;
        float s0 = 0.f, s1 = 0.f, s2 = 0.f, s3 = 0.f;
#pragma unroll
        for (int i = 0; i < 32; ++i) {
            float4 a = ((const float4*)xs)[i];
            float4 q0 = ((const float4*)(cb + ((size_t)(tid) * NG + g) * ND))[i];
            float4 q1 = ((const float4*)(cb + ((size_t)(tid + 256) * NG + g) * ND))[i];
            float4 q2 = ((const float4*)(cb + ((size_t)(tid + 512) * NG + g) * ND))[i];
            float4 q3 = ((const float4*)(cb + ((size_t)(tid + 768) * NG + g) * ND))[i];
            s0 = fmaf(a.x, q0.x, s0); s0 = fmaf(a.y, q0.y, s0);
            s0 = fmaf(a.z, q0.z, s0); s0 = fmaf(a.w, q0.w, s0);
            s1 = fmaf(a.x, q1.x, s1); s1 = fmaf(a.y, q1.y, s1);
            s1 = fmaf(a.z, q1.z, s1); s1 = fmaf(a.w, q1.w, s1);
            s2 = fmaf(a.x, q2.x, s2); s2 = fmaf(a.y, q2.y, s2);
            s2 = fmaf(a.z, q2.z, s2); s2 = fmaf(a.w, q2.w, s2);
            s3 = fmaf(a.x, q3.x, s3); s3 = fmaf(a.y, q3.y, s3);
            s3 = fmaf(a.z, q3.z, s3); s3 = fmaf(a.w, q3.w, s3);
        }
        float dd[4] = {s0, s1, s2, s3};
#pragma unroll
        for (int jj = 0; jj < 4; ++jj) {
            int c = tid + 256 * jj;
            float d = __fadd_rn(__fsub_rn(x2v, __fmul_rn(2.0f, dd[jj])),
                                c2w[(size_t)c * NG + g]);
            if (d < best || (d == best && c < bid)) { best = d; bid = c; }
        }
#pragma unroll
        for (int m = 1; m < 64; m <<= 1) {
            float od = __shfl_xor(best, m);
            int ob = __shfl_xor(bid, m);
            if (od < best || (od == best && ob < bid)) { best = od; bid = ob; }
        }
        if (lane == 0) redw[w] = make_float2(best, __int_as_float(bid));
        __syncthreads();
        if (tid == 0) {
            float b2 = redw[0].x;
            int i2 = __float_as_int(redw[0].y);
#pragma unroll
            for (int ww = 1; ww < 4; ++ww) {
                float ob = redw[ww].x;
                int oi = __float_as_int(redw[ww].y);
                if (ob < b2 || (ob == b2 && oi < i2)) { b2 = ob; i2 = oi; }
            }
            ws_ids[idx] = i2;
            out_ids[idx] = pad[idx >> 3] ? -1.0f : (float)i2;
        }
    }
}

// ---------------------------------------------------------------------------
// gather quantized (masked), write quantized_st, per-token loss partial
// ---------------------------------------------------------------------------
__global__ __launch_bounds__(256) void gather_kernel(
    const float* __restrict__ x, const int* __restrict__ pad,
    const float* __restrict__ cb, const int* __restrict__ ws_ids,
    float* __restrict__ out_q, float* __restrict__ ws_loss) {
    const int n = blockIdx.x;
    const int tid = threadIdx.x;
    const int g = tid >> 5;
    const int d4 = tid & 31;
    const int p = pad[n];

    float4 q = make_float4(0.f, 0.f, 0.f, 0.f);
    float s = 0.f;
    if (!p) {
        int id = ws_ids[n * NG + g];
        q = ((const float4*)(cb + ((size_t)id * NG + g) * ND))[d4];
        float4 a = ((const float4*)(x + (size_t)n * (NG * ND)))[tid];
        float e0 = q.x - a.x, e1 = q.y - a.y, e2 = q.z - a.z, e3 = q.w - a.w;
        s = e0 * e0 + e1 * e1 + e2 * e2 + e3 * e3;
    }
    ((float4*)(out_q + (size_t)n * (NG * ND)))[tid] = q;

    for (int off = 32; off > 0; off >>= 1) s += __shfl_down(s, off);
    __shared__ float red[4];
    int w = tid >> 6, lane = tid & 63;
    if (lane == 0) red[w] = s;
    __syncthreads();
    if (tid == 0) ws_loss[n] = (red[0] + red[1]) + (red[2] + red[3]);
}

// ---------------------------------------------------------------------------
__global__ __launch_bounds__(256) void final_kernel(
    const int* __restrict__ pad, const float* __restrict__ ws_loss,
    float* __restrict__ out_l) {
    __shared__ float sr[256];
    __shared__ int mr[256];
    const int tid = threadIdx.x;
    float s = 0.f;
    int m = 0;
    for (int i = tid; i < BT; i += 256) {
        s += ws_loss[i];
        m += 1 - pad[i];
    }
    sr[tid] = s;
    mr[tid] = m;
    __syncthreads();
    for (int st = 128; st > 0; st >>= 1) {
        if (tid < st) { sr[tid] += sr[tid + st]; mr[tid] += mr[tid + st]; }
        __syncthreads();
    }
    if (tid == 0) {
        float k = sr[0] / (float)mr[0];
        out_l[0] = k;
        out_l[1] = k;
        out_l[2] = k + k;
    }
}

// ---------------------------------------------------------------------------
extern "C" void kernel_launch(void* const* d_in, const int* in_sizes, int n_in,
                              void* d_out, int out_size, void* d_ws, size_t ws_size,
                              hipStream_t stream) {
    const float* x = (const float*)d_in[0];
    const int* pad = (const int*)d_in[1];
    const float* cb = (const float*)d_in[2];
    float* out = (float*)d_out;
    float* ws = (float*)d_ws;

    float* ws_c2a = ws + OFF_C2A;
    float* ws_c2b = ws + OFF_C2B;
    int* ws_ids = (int*)(ws + OFF_IDS);
    float* ws_loss = ws + OFF_LOSS;
    int* ws_cnt = (int*)(ws + OFF_CNT);
    int* ws_flags = (int*)(ws + OFF_FLAGS);
    f16* cbh = (f16*)(ws + OFF_CBH);
    f16* cbl = (f16*)(ws + OFF_CBL);

    prep_kernel<<<NV * NG / 256, 256, 0, stream>>>(cb, cbh, cbl, ws_c2a, ws_c2b,
                                                   ws_cnt);
    mfma_gemm<<<(BT / BM) * NG, 256, 0, stream>>>(x, cbh, cbl, ws_c2b, pad,
                                                  ws_ids, out + OUT_IDS, ws_cnt,
                                                  ws_flags);
    recheck<<<2048, 256, 0, stream>>>(x, pad, cb, ws_c2a, ws_cnt, ws_flags,
                                      ws_ids, out + OUT_IDS);
    gather_kernel<<<BT, 256, 0, stream>>>(x, pad, cb, ws_ids, out + OUT_Q, ws_loss);
    final_kernel<<<1, 256, 0, stream>>>(pad, ws_loss, out + OUT_L);
}

// Round 10
// 121.998 us; speedup vs baseline: 34.9457x; 1.0862x over previous
//
#include <hip/hip_runtime.h>
#include <math.h>

typedef _Float16 f16;
typedef f16 half8 __attribute__((ext_vector_type(8)));
typedef float f32x4 __attribute__((ext_vector_type(4)));

// Problem sizes: B=4, T=2048, G=8, D=128, V=1024
#define BT 8192
#define NG 8
#define ND 128
#define NV 1024
#define MARGIN 0.02f
#define BM 64        // tokens per block
#define BN 32        // codes per tile
#define NT 32        // code tiles

// d_out layout (float32): ids[65536] | quantized_st[8388608] | 3 losses
#define OUT_IDS 0
#define OUT_Q   65536
#define OUT_L   (65536 + 8388608)

// ws float offsets (~4.8 MB)
#define OFF_C2A   0                        // c2 [v*8+g] (recheck)     (8192)
#define OFF_C2B   8192                     // c2 [g*NV+v] (gemm)       (8192)
#define OFF_IDS   16384                    // ids int                  (65536)
#define OFF_LOSS  81920                    // per-token loss           (8192)
#define OFF_CNT   90112                    // flag count               (8)
#define OFF_FLAGS 90120                    // flag list                (65536)
#define OFF_CBH   155656                   // cbh fp16 swizzled stream (524288 fl)
#define OFF_CBL   (OFF_CBH + 524288)       // cbl fp16 swizzled stream (524288 fl)

// ---------------------------------------------------------------------------
// async global->LDS, 16B per lane (linear dest, pre-swizzled source)
// ---------------------------------------------------------------------------
__device__ __forceinline__ void gll16(const f16* g, f16* l) {
    __builtin_amdgcn_global_load_lds(
        (const __attribute__((address_space(1))) unsigned int*)g,
        (__attribute__((address_space(3))) unsigned int*)l, 16, 0, 0);
}

// ---------------------------------------------------------------------------
// prep: c2 (both layouts, R1-exact pairwise-8 order) + fp16 h/l split of the
// codebook written as PRE-SWIZZLED g-blocked 32-row tile chunks:
// stream[(g*32+cn)*4096 + rl*128 + j*8 + e] = cb[v=cn*32+rl][(j^(rl&7))*8+e]
// so a linear global_load_lds fill yields the XOR-swizzled LDS tile.
// ---------------------------------------------------------------------------
__global__ __launch_bounds__(256) void prep_kernel(
    const float* __restrict__ cb, f16* __restrict__ cbh, f16* __restrict__ cbl,
    float* __restrict__ c2a, float* __restrict__ c2b, int* __restrict__ cnt) {
    int idx = blockIdx.x * 256 + threadIdx.x;   // v*8+g
    if (idx == 0) *cnt = 0;
    int v = idx >> 3, g = idx & 7;
    const float* row = cb + (size_t)idx * ND;

    float r[8];
#pragma unroll
    for (int j = 0; j < 8; ++j) r[j] = 0.0f;
#pragma unroll
    for (int k = 0; k < 16; ++k)
#pragma unroll
        for (int j = 0; j < 8; ++j) {
            float c = row[k * 8 + j];
            r[j] = __fadd_rn(r[j], __fmul_rn(c, c));
        }
    float s = __fadd_rn(
        __fadd_rn(__fadd_rn(r[0], r[1]), __fadd_rn(r[2], r[3])),
        __fadd_rn(__fadd_rn(r[4], r[5]), __fadd_rn(r[6], r[7])));
    c2a[idx] = s;
    c2b[g * NV + v] = s;

    int cn = v >> 5, rl = v & 31;
    size_t base = ((size_t)(g * 32 + cn)) * 4096 + rl * 128;
#pragma unroll
    for (int j = 0; j < 16; ++j) {
        int js = (j ^ (rl & 7)) * 8;
        half8 h, l;
#pragma unroll
        for (int e = 0; e < 8; ++e) {
            float vv = row[js + e];
            f16 hh = (f16)vv;
            h[e] = hh;
            l[e] = (f16)(vv - (float)hh);
        }
        *(half8*)(cbh + base + j * 8) = h;
        *(half8*)(cbl + base + j * 8) = l;
    }
}

// ---------------------------------------------------------------------------
// MFMA distance GEMM. Block = 64 tokens x one g; 4 waves = 2 token-halves
// (wr) x 2 code-halves (wc); wave = 32 tokens x 16 codes per tile.
// A fp32 read once, fp16-split in regs. B: 32 tiles of 32 codes, DOUBLE-
// buffered LDS (2 x 16 KB) filled by global_load_lds issued BEFORE compute
// so the DMA flies under the tile's 24 MFMA + 8 ds_read; one barrier/tile.
// c2 staged once in LDS (no in-loop global loads). 4 blocks/CU (36KB LDS).
// s = xh*ch + xh*cl + xl*ch; d' = c2 - 2s (x2 cancels in argmin).
// Exact per-thread running top-2 across all tiles; one merge at block end.
// Flag iff d2 - d1 < MARGIN => exact recheck (sound).
// ---------------------------------------------------------------------------
__global__ __launch_bounds__(256, 4) void mfma_gemm(
    const float* __restrict__ x, const f16* __restrict__ cbh,
    const f16* __restrict__ cbl, const float* __restrict__ c2b,
    const int* __restrict__ pad, int* __restrict__ ws_ids,
    float* __restrict__ out_ids, int* __restrict__ cnt,
    int* __restrict__ flags) {
    __shared__ __align__(16) f16 Bh[2][BN * ND];   // 2 x 8 KB
    __shared__ __align__(16) f16 Bl[2][BN * ND];   // 2 x 8 KB
    __shared__ __align__(16) float c2s[NV];        // 4 KB

    const int tid = threadIdx.x;
    const int b = blockIdx.x;
    const int g = b & 7;
    const int tok0 = (b >> 3) * BM;
    const int lane = tid & 63;
    const int w = tid >> 6;
    const int wr = w & 1, wc = w >> 1;
    const int l15 = lane & 15, l4 = lane >> 4;

    // prologue: issue DMA for c2 + tile 0, then load/split A while DMA flies
    gll16((const f16*)(c2b + (size_t)g * NV) + tid * 8, (f16*)c2s + tid * 8);
    {
        const f16* sh = cbh + ((size_t)(g * 32 + 0)) * 4096;
        const f16* sl = cbl + ((size_t)(g * 32 + 0)) * 4096;
#pragma unroll
        for (int it = 0; it < 2; ++it) {
            int off = it * 2048 + tid * 8;
            gll16(sh + off, &Bh[0][off]);
            gll16(sl + off, &Bl[0][off]);
        }
    }

    // ---- A: load fp32 once, split to fp16 h/l in registers (32 tokens) ----
    half8 ah[4][2], al[4][2];   // [kk][ti]
#pragma unroll
    for (int kk = 0; kk < 4; ++kk)
#pragma unroll
        for (int ti = 0; ti < 2; ++ti) {
            const float* ap = x + ((size_t)(tok0 + wr * 32 + ti * 16 + l15) * NG + g) * ND
                              + kk * 32 + l4 * 8;
            float4 p0 = *(const float4*)ap, p1 = *(const float4*)(ap + 4);
            float v[8] = {p0.x, p0.y, p0.z, p0.w, p1.x, p1.y, p1.z, p1.w};
            half8 h, l;
#pragma unroll
            for (int j = 0; j < 8; ++j) {
                f16 hh = (f16)v[j];
                h[j] = hh;
                l[j] = (f16)(v[j] - (float)hh);
            }
            ah[kk][ti] = h;
            al[kk][ti] = l;
        }

    float d1s[2][4], d2s[2][4];
    int ids_[2][4];
#pragma unroll
    for (int ti = 0; ti < 2; ++ti)
#pragma unroll
        for (int r = 0; r < 4; ++r) {
            d1s[ti][r] = INFINITY;
            d2s[ti][r] = INFINITY;
            ids_[ti][r] = 0;
        }

    __syncthreads();   // drains prologue DMA: c2 + tile 0 ready

    int buf = 0;
#pragma unroll 1
    for (int cn = 0; cn < NT; ++cn) {
        // issue next tile's DMA into the other buffer (flies under compute)
        if (cn + 1 < NT) {
            const f16* sh = cbh + ((size_t)(g * 32 + cn + 1)) * 4096;
            const f16* sl = cbl + ((size_t)(g * 32 + cn + 1)) * 4096;
#pragma unroll
            for (int it = 0; it < 2; ++it) {
                int off = it * 2048 + tid * 8;
                gll16(sh + off, &Bh[buf ^ 1][off]);
                gll16(sl + off, &Bl[buf ^ 1][off]);
            }
        }

        const int rw = wc * 16 + l15;
        const int cbase = cn * BN + rw;
        f32x4 acc[2];
#pragma unroll
        for (int ti = 0; ti < 2; ++ti) acc[ti] = (f32x4){0.f, 0.f, 0.f, 0.f};

#pragma unroll
        for (int kk = 0; kk < 4; ++kk) {
            int off = rw * 128 + (((kk * 4 + l4) ^ (rw & 7)) << 3);
            half8 bh = *(const half8*)(&Bh[buf][off]);
            half8 bl = *(const half8*)(&Bl[buf][off]);
#pragma unroll
            for (int ti = 0; ti < 2; ++ti)
                acc[ti] = __builtin_amdgcn_mfma_f32_16x16x32_f16(
                    ah[kk][ti], bh, acc[ti], 0, 0, 0);
#pragma unroll
            for (int ti = 0; ti < 2; ++ti)
                acc[ti] = __builtin_amdgcn_mfma_f32_16x16x32_f16(
                    ah[kk][ti], bl, acc[ti], 0, 0, 0);
#pragma unroll
            for (int ti = 0; ti < 2; ++ti)
                acc[ti] = __builtin_amdgcn_mfma_f32_16x16x32_f16(
                    al[kk][ti], bh, acc[ti], 0, 0, 0);
        }

        // epilogue: d' = c2 - 2s; per-thread running exact top-2
        float c2v = c2s[cbase];
#pragma unroll
        for (int ti = 0; ti < 2; ++ti)
#pragma unroll
            for (int r = 0; r < 4; ++r) {
                float dv = fmaf(-2.0f, acc[ti][r], c2v);
                if (dv < d1s[ti][r]) {
                    d2s[ti][r] = d1s[ti][r];
                    d1s[ti][r] = dv;
                    ids_[ti][r] = cbase;
                } else {
                    d2s[ti][r] = fminf(d2s[ti][r], dv);
                }
            }

        __syncthreads();   // drains prefetch DMA + all waves done with buf
        buf ^= 1;
    }

    // final merge: 4 xor-shuffle stages across l15, then across wc via LDS
    float4* red = (float4*)&Bh[0][0];   // overlay (Bh free after last barrier)
#pragma unroll
    for (int ti = 0; ti < 2; ++ti)
#pragma unroll
        for (int r = 0; r < 4; ++r) {
            float d1 = d1s[ti][r], d2 = d2s[ti][r];
            int id = ids_[ti][r];
#pragma unroll
            for (int m = 1; m < 16; m <<= 1) {
                float od1 = __shfl_xor(d1, m);
                float od2 = __shfl_xor(d2, m);
                int oid = __shfl_xor(id, m);
                if (od1 < d1) { d2 = fminf(d1, od2); d1 = od1; id = oid; }
                else d2 = fminf(d2, fminf(od1, od2));
            }
            if (l15 == 0)
                red[wc * BM + wr * 32 + ti * 16 + l4 * 4 + r] =
                    make_float4(d1, __int_as_float(id), d2, 0.f);
        }
    __syncthreads();

    if (tid < BM) {
        float4 a = red[tid], c = red[BM + tid];
        float d1 = a.x, d2 = a.z;
        int id = __float_as_int(a.y);
        if (c.x < d1) { d2 = fminf(d1, c.z); d1 = c.x; id = __float_as_int(c.y); }
        else d2 = fminf(d2, fminf(c.x, c.z));
        int tok = tok0 + tid;
        int idx = tok * NG + g;
        ws_ids[idx] = id;
        out_ids[idx] = pad[tok] ? -1.0f : (float)id;
        if (d2 - d1 < MARGIN) {
            int pos = atomicAdd(cnt, 1);
            flags[pos] = idx;
        }
    }
}

// ---------------------------------------------------------------------------
// exact fp32 recheck, BLOCK per flag: 256 threads, 4 codes/thread (ILP 4),
// x row staged in LDS (broadcast reads). R1-identical per-code arithmetic;
// index tie-break reduce == first-occurrence argmin.
// ---------------------------------------------------------------------------
__global__ __launch_bounds__(256) void recheck(
    const float* __restrict__ x, const int* __restrict__ pad,
    const float* __restrict__ cb, const float* __restrict__ c2w,
    const int* __restrict__ cnt, const int* __restrict__ flags,
    int* __restrict__ ws_ids, float* __restrict__ out_ids) {
    __shared__ __align__(16) float xs[ND];
    __shared__ float2 redw[4];
    const int tid = threadIdx.x;
    const int lane = tid & 63;
    const int w = tid >> 6;
    const int n_f = cnt[0];

    for (int f = blockIdx.x; f < n_f; f += gridDim.x) {
        int idx = flags[f];
        int g = idx & 7;
        __syncthreads();   // previous iteration's reads done
        if (tid < 32)
            ((float4*)xs)[tid] = ((const float4*)(x + (size_t)idx * ND))[tid];
        __syncthreads();

        // exact x2 (R1 pairwise-8 order), redundant per thread (broadcast)
        float rr[8];
#pragma unroll
        for (int j = 0; j < 8; ++j) rr[j] = 0.0f;
#pragma unroll
        for (int i = 0; i < 32; ++i) {
            float4 v = ((const float4*)xs)[i];
            int j0 = (i * 4) & 7;
            rr[j0 + 0] = __fadd_rn(rr[j0 + 0], __fmul_rn(v.x, v.x));
            rr[j0 + 1] = __fadd_rn(rr[j0 + 1], __fmul_rn(v.y, v.y));
            rr[j0 + 2] = __fadd_rn(rr[j0 + 2], __fmul_rn(v.z, v.z));
            rr[j0 + 3] = __fadd_rn(rr[j0 + 3], __fmul_rn(v.w, v.w));
        }
        float x2v = __fadd_rn(
            __fadd_rn(__fadd_rn(rr[0], rr[1]), __fadd_rn(rr[2], rr[3])),
            __fadd_rn(__fadd_rn(rr[4], rr[5]), __fadd_rn(rr[6], rr[7])));

        // 4 codes per thread, independent chains
        float best = INFINITY;
        int bid = 0x7FFFFFFF;
        float s0 = 0.f, s1 = 0.f, s2 = 0.f, s3 = 0.f;
#pragma unroll
        for (int i = 0; i < 32; ++i) {
            float4 a = ((const float4*)xs)[i];
            float4 q0 = ((const float4*)(cb + ((size_t)(tid) * NG + g) * ND))[i];
            float4 q1 = ((const float4*)(cb + ((size_t)(tid + 256) * NG + g) * ND))[i];
            float4 q2 = ((const float4*)(cb + ((size_t)(tid + 512) * NG + g) * ND))[i];
            float4 q3 = ((const float4*)(cb + ((size_t)(tid + 768) * NG + g) * ND))[i];
            s0 = fmaf(a.x, q0.x, s0); s0 = fmaf(a.y, q0.y, s0);
            s0 = fmaf(a.z, q0.z, s0); s0 = fmaf(a.w, q0.w, s0);
            s1 = fmaf(a.x, q1.x, s1); s1 = fmaf(a.y, q1.y, s1);
            s1 = fmaf(a.z, q1.z, s1); s1 = fmaf(a.w, q1.w, s1);
            s2 = fmaf(a.x, q2.x, s2); s2 = fmaf(a.y, q2.y, s2);
            s2 = fmaf(a.z, q2.z, s2); s2 = fmaf(a.w, q2.w, s2);
            s3 = fmaf(a.x, q3.x, s3); s3 = fmaf(a.y, q3.y, s3);
            s3 = fmaf(a.z, q3.z, s3); s3 = fmaf(a.w, q3.w, s3);
        }
        float dd[4] = {s0, s1, s2, s3};
#pragma unroll
        for (int jj = 0; jj < 4; ++jj) {
            int c = tid + 256 * jj;
            float d = __fadd_rn(__fsub_rn(x2v, __fmul_rn(2.0f, dd[jj])),
                                c2w[(size_t)c * NG + g]);
            if (d < best || (d == best && c < bid)) { best = d; bid = c; }
        }
#pragma unroll
        for (int m = 1; m < 64; m <<= 1) {
            float od = __shfl_xor(best, m);
            int ob = __shfl_xor(bid, m);
            if (od < best || (od == best && ob < bid)) { best = od; bid = ob; }
        }
        if (lane == 0) redw[w] = make_float2(best, __int_as_float(bid));
        __syncthreads();
        if (tid == 0) {
            float b2 = redw[0].x;
            int i2 = __float_as_int(redw[0].y);
#pragma unroll
            for (int ww = 1; ww < 4; ++ww) {
                float ob = redw[ww].x;
                int oi = __float_as_int(redw[ww].y);
                if (ob < b2 || (ob == b2 && oi < i2)) { b2 = ob; i2 = oi; }
            }
            ws_ids[idx] = i2;
            out_ids[idx] = pad[idx >> 3] ? -1.0f : (float)i2;
        }
    }
}

// ---------------------------------------------------------------------------
// gather quantized (masked), write quantized_st, per-token loss partial
// ---------------------------------------------------------------------------
__global__ __launch_bounds__(256) void gather_kernel(
    const float* __restrict__ x, const int* __restrict__ pad,
    const float* __restrict__ cb, const int* __restrict__ ws_ids,
    float* __restrict__ out_q, float* __restrict__ ws_loss) {
    const int n = blockIdx.x;
    const int tid = threadIdx.x;
    const int g = tid >> 5;
    const int d4 = tid & 31;
    const int p = pad[n];

    float4 q = make_float4(0.f, 0.f, 0.f, 0.f);
    float s = 0.f;
    if (!p) {
        int id = ws_ids[n * NG + g];
        q = ((const float4*)(cb + ((size_t)id * NG + g) * ND))[d4];
        float4 a = ((const float4*)(x + (size_t)n * (NG * ND)))[tid];
        float e0 = q.x - a.x, e1 = q.y - a.y, e2 = q.z - a.z, e3 = q.w - a.w;
        s = e0 * e0 + e1 * e1 + e2 * e2 + e3 * e3;
    }
    ((float4*)(out_q + (size_t)n * (NG * ND)))[tid] = q;

    for (int off = 32; off > 0; off >>= 1) s += __shfl_down(s, off);
    __shared__ float red[4];
    int w = tid >> 6, lane = tid & 63;
    if (lane == 0) red[w] = s;
    __syncthreads();
    if (tid == 0) ws_loss[n] = (red[0] + red[1]) + (red[2] + red[3]);
}

// ---------------------------------------------------------------------------
__global__ __launch_bounds__(256) void final_kernel(
    const int* __restrict__ pad, const float* __restrict__ ws_loss,
    float* __restrict__ out_l) {
    __shared__ float sr[256];
    __shared__ int mr[256];
    const int tid = threadIdx.x;
    float s = 0.f;
    int m = 0;
    for (int i = tid; i < BT; i += 256) {
        s += ws_loss[i];
        m += 1 - pad[i];
    }
    sr[tid] = s;
    mr[tid] = m;
    __syncthreads();
    for (int st = 128; st > 0; st >>= 1) {
        if (tid < st) { sr[tid] += sr[tid + st]; mr[tid] += mr[tid + st]; }
        __syncthreads();
    }
    if (tid == 0) {
        float k = sr[0] / (float)mr[0];
        out_l[0] = k;
        out_l[1] = k;
        out_l[2] = k + k;
    }
}

// ---------------------------------------------------------------------------
extern "C" void kernel_launch(void* const* d_in, const int* in_sizes, int n_in,
                              void* d_out, int out_size, void* d_ws, size_t ws_size,
                              hipStream_t stream) {
    const float* x = (const float*)d_in[0];
    const int* pad = (const int*)d_in[1];
    const float* cb = (const float*)d_in[2];
    float* out = (float*)d_out;
    float* ws = (float*)d_ws;

    float* ws_c2a = ws + OFF_C2A;
    float* ws_c2b = ws + OFF_C2B;
    int* ws_ids = (int*)(ws + OFF_IDS);
    float* ws_loss = ws + OFF_LOSS;
    int* ws_cnt = (int*)(ws + OFF_CNT);
    int* ws_flags = (int*)(ws + OFF_FLAGS);
    f16* cbh = (f16*)(ws + OFF_CBH);
    f16* cbl = (f16*)(ws + OFF_CBL);

    prep_kernel<<<NV * NG / 256, 256, 0, stream>>>(cb, cbh, cbl, ws_c2a, ws_c2b,
                                                   ws_cnt);
    mfma_gemm<<<(BT / BM) * NG, 256, 0, stream>>>(x, cbh, cbl, ws_c2b, pad,
                                                  ws_ids, out + OUT_IDS, ws_cnt,
                                                  ws_flags);
    recheck<<<2048, 256, 0, stream>>>(x, pad, cb, ws_c2a, ws_cnt, ws_flags,
                                      ws_ids, out + OUT_IDS);
    gather_kernel<<<BT, 256, 0, stream>>>(x, pad, cb, ws_ids, out + OUT_Q, ws_loss);
    final_kernel<<<1, 256, 0, stream>>>(pad, ws_loss, out + OUT_L);
}